// Round 5
// baseline (311.287 us; speedup 1.0000x reference)
//
#include <hip/hip_runtime.h>

typedef __bf16 bf16x8 __attribute__((ext_vector_type(8)));
typedef float f32x4 __attribute__((ext_vector_type(4)));
typedef unsigned short us8 __attribute__((ext_vector_type(8)));

#define GAS __attribute__((address_space(1)))
#define LAS __attribute__((address_space(3)))

__device__ __forceinline__ unsigned short f32_to_bf16(float f) {
    unsigned int u = __float_as_uint(f);
    u += 0x7FFFu + ((u >> 16) & 1u);   // round-to-nearest-even
    return (unsigned short)(u >> 16);
}

__device__ __forceinline__ float bf16_to_f32(unsigned short h) {
    return __uint_as_float((unsigned int)h << 16);
}

__device__ __forceinline__ void load16(const unsigned short* g, unsigned short* l) {
    // async global->LDS, 16B per lane; LDS dest is wave-uniform base + lane*16
    __builtin_amdgcn_global_load_lds((GAS unsigned int*)g, (LAS unsigned int*)l, 16, 0, 0);
}

// ---------------------------------------------------------------------------
// fp32 -> bf16 elementwise convert (x)
// ---------------------------------------------------------------------------
__global__ __launch_bounds__(256) void convert_f32_bf16(
    const float* __restrict__ in, unsigned short* __restrict__ out, int n4)
{
    int i = blockIdx.x * 256 + threadIdx.x;
    if (i < n4) {
        float4 v = ((const float4*)in)[i];
        ushort4 o;
        o.x = f32_to_bf16(v.x); o.y = f32_to_bf16(v.y);
        o.z = f32_to_bf16(v.z); o.w = f32_to_bf16(v.w);
        ((ushort4*)out)[i] = o;
    }
}

// ---------------------------------------------------------------------------
// 768x768 fp32 -> bf16 transpose (three weights via blockIdx.z)
// ---------------------------------------------------------------------------
__global__ __launch_bounds__(1024) void transpose_w(
    const float* __restrict__ W0, const float* __restrict__ W1, const float* __restrict__ W2,
    unsigned short* __restrict__ T0, unsigned short* __restrict__ T1, unsigned short* __restrict__ T2)
{
    __shared__ float tile[32][33];
    const float* W = (blockIdx.z == 0) ? W0 : (blockIdx.z == 1) ? W1 : W2;
    unsigned short* T = (blockIdx.z == 0) ? T0 : (blockIdx.z == 1) ? T1 : T2;
    int r0 = blockIdx.y * 32, c0 = blockIdx.x * 32;
    tile[threadIdx.y][threadIdx.x] = W[(size_t)(r0 + threadIdx.y) * 768 + c0 + threadIdx.x];
    __syncthreads();
    T[(size_t)(c0 + threadIdx.y) * 768 + r0 + threadIdx.x] = f32_to_bf16(tile[threadIdx.x][threadIdx.y]);
}

// ---------------------------------------------------------------------------
// bf16 [8192,768] -> bf16 [768,8192] transpose (V -> V^T)
// ---------------------------------------------------------------------------
__global__ __launch_bounds__(1024) void transpose_v(
    const unsigned short* __restrict__ V, unsigned short* __restrict__ Vt)
{
    __shared__ unsigned short tile[32][33];
    int r0 = blockIdx.y * 32, c0 = blockIdx.x * 32;   // r over 8192, c over 768
    tile[threadIdx.y][threadIdx.x] = V[(size_t)(r0 + threadIdx.y) * 768 + c0 + threadIdx.x];
    __syncthreads();
    Vt[(size_t)(c0 + threadIdx.y) * 8192 + r0 + threadIdx.x] = tile[threadIdx.x][threadIdx.y];
}

// ---------------------------------------------------------------------------
// NT GEMM (m97 structure + XOR bank-swizzle): C = alpha * A[M,K] . B[N,K]^T
// LDS slot (row, cc) holds global chunk (row, cc ^ (row&7)); fragment reads
// use chunk^(row&7) -> quad's 16 rows spread over 8 bank groups (2-way, free).
// ---------------------------------------------------------------------------
template <typename CT>
__global__ __launch_bounds__(256) void gemm_nt(
    const unsigned short* __restrict__ A, const unsigned short* __restrict__ B,
    CT* __restrict__ C, int K, int lda, int ldb, int ldc,
    size_t sA, size_t sB, size_t sC, float alpha)
{
    A += (size_t)blockIdx.z * sA;
    B += (size_t)blockIdx.z * sB;
    C += (size_t)blockIdx.z * sC;
    const int m0 = blockIdx.y * 128;
    const int n0 = blockIdx.x * 128;
    const int t = threadIdx.x;
    const int lane = t & 63;
    const int w = t >> 6;
    const int wm = (w >> 1) * 64;   // wave row offset in tile
    const int wn = (w & 1) * 64;    // wave col offset in tile

    __shared__ unsigned short At[128 * 64];
    __shared__ unsigned short Bt[128 * 64];

    f32x4 acc[4][4];
#pragma unroll
    for (int i = 0; i < 4; ++i)
#pragma unroll
        for (int j = 0; j < 4; ++j) acc[i][j] = (f32x4){0.f, 0.f, 0.f, 0.f};

    const int r15 = lane & 15;
    const int qa = lane >> 4;       // fragment chunk index within 32-elem half

    for (int k0 = 0; k0 < K; k0 += 64) {
#pragma unroll
        for (int i = 0; i < 4; ++i) {
            const int c = i * 256 + t;            // LDS chunk id (8 bf16 each)
            const int row = c >> 3;
            const int cc = (c & 7) ^ (row & 7);   // swizzled global source chunk
            load16(A + (size_t)(m0 + row) * lda + k0 + cc * 8, &At[c * 8]);
            load16(B + (size_t)(n0 + row) * ldb + k0 + cc * 8, &Bt[c * 8]);
        }
        __syncthreads();

#pragma unroll
        for (int ks = 0; ks < 2; ++ks) {
            bf16x8 af[4], bf[4];
#pragma unroll
            for (int mi = 0; mi < 4; ++mi) {
                const int row = wm + mi * 16 + r15;
                af[mi] = *(const bf16x8*)&At[row * 64 + (((ks << 2) + qa) ^ (row & 7)) * 8];
            }
#pragma unroll
            for (int ni = 0; ni < 4; ++ni) {
                const int row = wn + ni * 16 + r15;
                bf[ni] = *(const bf16x8*)&Bt[row * 64 + (((ks << 2) + qa) ^ (row & 7)) * 8];
            }
#pragma unroll
            for (int mi = 0; mi < 4; ++mi)
#pragma unroll
                for (int ni = 0; ni < 4; ++ni)
                    acc[mi][ni] = __builtin_amdgcn_mfma_f32_16x16x32_bf16(
                        af[mi], bf[ni], acc[mi][ni], 0, 0, 0);
        }
        __syncthreads();
    }

    // epilogue: C/D layout col=lane&15, row=(lane>>4)*4+reg  [m89/m91 verified]
    const int cr = (lane >> 4) * 4;
#pragma unroll
    for (int mi = 0; mi < 4; ++mi) {
#pragma unroll
        for (int ni = 0; ni < 4; ++ni) {
            const int gm = m0 + wm + mi * 16 + cr;
            const int gn = n0 + wn + ni * 16 + r15;
#pragma unroll
            for (int r = 0; r < 4; ++r) {
                float v = alpha * acc[mi][ni][r];
                if constexpr (sizeof(CT) == 2)
                    C[(size_t)(gm + r) * ldc + gn] = (CT)f32_to_bf16(v);
                else
                    C[(size_t)(gm + r) * ldc + gn] = v;
            }
        }
    }
}

// ---------------------------------------------------------------------------
// Split-K O-GEMM, XCD-grouped swizzle + LDS bank swizzle. 1536 blocks, z=8.
//   u = m*8 + split*2 + batch ; f = (u%8) + 8*(n + 6*(u/8))
// K-chunk = 1024. Part[z = split*2+batch][4096][768] fp32.
// ---------------------------------------------------------------------------
__global__ __launch_bounds__(256) void gemm_nt_splitk(
    const unsigned short* __restrict__ P, const unsigned short* __restrict__ Vt,
    float* __restrict__ Part)
{
    const int f = blockIdx.x;
    const int r8 = f & 7;
    const int tq = f >> 3;            // 0..191
    const int n  = tq % 6;
    const int v  = tq / 6;            // 0..31
    const int u  = v * 8 + r8;        // 0..255
    const int batch = u & 1;
    const int split = (u >> 1) & 3;
    const int m = u >> 3;             // 0..31

    const unsigned short* A = P + (size_t)batch * 16777216 + (size_t)split * 1024;
    const unsigned short* B = Vt + (size_t)batch * 4096 + (size_t)split * 1024;
    float* C = Part + (size_t)(split * 2 + batch) * 3145728;
    const int lda = 4096, ldb = 8192, ldc = 768;
    const int m0 = m * 128;
    const int n0 = n * 128;
    const int t = threadIdx.x;
    const int lane = t & 63;
    const int w = t >> 6;
    const int wm = (w >> 1) * 64;
    const int wn = (w & 1) * 64;

    __shared__ unsigned short At[128 * 64];
    __shared__ unsigned short Bt[128 * 64];

    f32x4 acc[4][4];
#pragma unroll
    for (int i = 0; i < 4; ++i)
#pragma unroll
        for (int j = 0; j < 4; ++j) acc[i][j] = (f32x4){0.f, 0.f, 0.f, 0.f};

    const int r15 = lane & 15;
    const int qa = lane >> 4;

    for (int k0 = 0; k0 < 1024; k0 += 64) {
#pragma unroll
        for (int i = 0; i < 4; ++i) {
            const int c = i * 256 + t;
            const int row = c >> 3;
            const int cc = (c & 7) ^ (row & 7);
            load16(A + (size_t)(m0 + row) * lda + k0 + cc * 8, &At[c * 8]);
            load16(B + (size_t)(n0 + row) * ldb + k0 + cc * 8, &Bt[c * 8]);
        }
        __syncthreads();

#pragma unroll
        for (int ks = 0; ks < 2; ++ks) {
            bf16x8 af[4], bf[4];
#pragma unroll
            for (int mi = 0; mi < 4; ++mi) {
                const int row = wm + mi * 16 + r15;
                af[mi] = *(const bf16x8*)&At[row * 64 + (((ks << 2) + qa) ^ (row & 7)) * 8];
            }
#pragma unroll
            for (int ni = 0; ni < 4; ++ni) {
                const int row = wn + ni * 16 + r15;
                bf[ni] = *(const bf16x8*)&Bt[row * 64 + (((ks << 2) + qa) ^ (row & 7)) * 8];
            }
#pragma unroll
            for (int mi = 0; mi < 4; ++mi)
#pragma unroll
                for (int ni = 0; ni < 4; ++ni)
                    acc[mi][ni] = __builtin_amdgcn_mfma_f32_16x16x32_bf16(
                        af[mi], bf[ni], acc[mi][ni], 0, 0, 0);
        }
        __syncthreads();
    }

    const int cr = (lane >> 4) * 4;
#pragma unroll
    for (int mi = 0; mi < 4; ++mi) {
#pragma unroll
        for (int ni = 0; ni < 4; ++ni) {
            const int gm = m0 + wm + mi * 16 + cr;
            const int gn = n0 + wn + ni * 16 + r15;
#pragma unroll
            for (int r = 0; r < 4; ++r)
                C[(size_t)(gm + r) * ldc + gn] = acc[mi][ni][r];
        }
    }
}

// ---------------------------------------------------------------------------
// Reduce 4 split-K partials: out4[i] = sum_s p4[i + s*1572864]
// (Part z = split*2+batch, z-stride 786432 float4; s-step = 2 z = 1572864;
//  s=0 term offset (batch)*786432 == i's batch half -> base index is i.)
// ---------------------------------------------------------------------------
__global__ __launch_bounds__(256) void reduce4(
    const float* __restrict__ Part, float* __restrict__ out)
{
    const size_t i = (size_t)blockIdx.x * 256 + threadIdx.x;  // float4 index
    const f32x4* p = (const f32x4*)Part;
    ((f32x4*)out)[i] = p[i] + p[i + 1572864] + p[i + 2 * 1572864] + p[i + 3 * 1572864];
}

// ---------------------------------------------------------------------------
// Row softmax: S (bf16, 4096 cols) -> P (bf16). One block per row.
// ---------------------------------------------------------------------------
__global__ __launch_bounds__(256) void softmax_rows_bf16(
    const unsigned short* __restrict__ S, unsigned short* __restrict__ P)
{
    const size_t row = blockIdx.x;
    const unsigned short* s = S + row * 4096;
    unsigned short* p = P + row * 4096;
    const int t = threadIdx.x;
    const int wv = t >> 6, ln = t & 63;

    us8 a = ((const us8*)s)[t];
    us8 b = ((const us8*)s)[t + 256];
    float f[16];
#pragma unroll
    for (int j = 0; j < 8; ++j) { f[j] = bf16_to_f32(a[j]); f[8 + j] = bf16_to_f32(b[j]); }

    float lmax = -1e30f;
#pragma unroll
    for (int j = 0; j < 16; ++j) lmax = fmaxf(lmax, f[j]);
#pragma unroll
    for (int off = 32; off > 0; off >>= 1) lmax = fmaxf(lmax, __shfl_down(lmax, off, 64));
    __shared__ float redm[4], reds[4];
    if (ln == 0) redm[wv] = lmax;
    __syncthreads();
    const float rmax = fmaxf(fmaxf(redm[0], redm[1]), fmaxf(redm[2], redm[3]));

    float lsum = 0.f;
#pragma unroll
    for (int j = 0; j < 16; ++j) { f[j] = __expf(f[j] - rmax); lsum += f[j]; }
#pragma unroll
    for (int off = 32; off > 0; off >>= 1) lsum += __shfl_down(lsum, off, 64);
    if (ln == 0) reds[wv] = lsum;
    __syncthreads();
    const float inv = 1.f / (reds[0] + reds[1] + reds[2] + reds[3]);

    us8 oa, ob;
#pragma unroll
    for (int j = 0; j < 8; ++j) {
        oa[j] = f32_to_bf16(f[j] * inv);
        ob[j] = f32_to_bf16(f[8 + j] * inv);
    }
    ((us8*)p)[t] = oa;
    ((us8*)p)[t + 256] = ob;
}

// ---------------------------------------------------------------------------
extern "C" void kernel_launch(void* const* d_in, const int* in_sizes, int n_in,
                              void* d_out, int out_size, void* d_ws, size_t ws_size,
                              hipStream_t stream) {
    const float* x  = (const float*)d_in[0];   // [2,4096,768]
    const float* Wq = (const float*)d_in[1];   // [768,768]
    const float* Wk = (const float*)d_in[2];
    const float* Wv = (const float*)d_in[3];
    float* out = (float*)d_out;                // [2,4096,768] fp32

    char* base = (char*)d_ws;
    size_t off = 0;
    auto alloc = [&](size_t b) { char* p = base + off; off += (b + 255) & ~(size_t)255; return p; };

    unsigned short* Xbf = (unsigned short*)alloc(8192ull * 768 * 2);   // x as bf16
    unsigned short* WqT = (unsigned short*)alloc(768ull * 768 * 2);    // W^T bf16, x3 contiguous
    unsigned short* WkT = (unsigned short*)alloc(768ull * 768 * 2);
    unsigned short* WvT = (unsigned short*)alloc(768ull * 768 * 2);
    unsigned short* Qb  = (unsigned short*)alloc(8192ull * 768 * 2);   // Q,K,V bf16, contiguous
    unsigned short* Kb  = (unsigned short*)alloc(8192ull * 768 * 2);
    unsigned short* Vb  = (unsigned short*)alloc(8192ull * 768 * 2);
    unsigned short* Vt  = (unsigned short*)alloc(768ull * 8192 * 2);   // V^T bf16 [768,8192]
    float*          Part = (float*)alloc(8ull * 3145728 * 4);          // split-K partials (100.7 MB)
    unsigned short* P   = (unsigned short*)alloc(2ull * 4096 * 4096 * 2); // softmax bf16
    unsigned short* Sbf = (unsigned short*)Part;                       // S bf16 overlays Part (dead by then)
    (void)ws_size; (void)in_sizes; (void)n_in; (void)out_size; (void)WkT;

    // 1) x -> bf16
    convert_f32_bf16<<<dim3(6144), dim3(256), 0, stream>>>(x, Xbf, 8192 * 768 / 4);
    // 2) W -> W^T bf16 (all three)
    transpose_w<<<dim3(24, 24, 3), dim3(32, 32), 0, stream>>>(Wq, Wk, Wv, WqT, WkT, WvT);
    // 3) Q,K,V = Xbf . W^T^T  (NT; z selects W and destination)
    gemm_nt<unsigned short><<<dim3(6, 64, 3), dim3(256), 0, stream>>>(
        Xbf, WqT, Qb, 768, 768, 768, 768,
        /*sA*/ 0, /*sB*/ 589824, /*sC*/ 6291456, 1.0f);
    // 4) V -> V^T bf16
    transpose_v<<<dim3(24, 256), dim3(32, 32), 0, stream>>>(Vb, Vt);
    // 5) S = (Q . K^T) / sqrt(768), bf16, per batch
    gemm_nt<unsigned short><<<dim3(32, 32, 2), dim3(256), 0, stream>>>(
        Qb, Kb, Sbf, 768, 768, 768, 4096,
        /*sA*/ 3145728ull, /*sB*/ 3145728ull, /*sC*/ 16777216ull, 0.03608439182435161f);
    // 6) row softmax (bf16 in) -> P bf16
    softmax_rows_bf16<<<dim3(8192), dim3(256), 0, stream>>>(Sbf, P);
    // 7) O = P . V via 4-way split-K (z=8 with batches), XCD-grouped swizzle
    gemm_nt_splitk<<<dim3(1536), dim3(256), 0, stream>>>(P, Vt, Part);
    reduce4<<<dim3(6144), dim3(256), 0, stream>>>(Part, out);
}